// Round 12
// baseline (227.437 us; speedup 1.0000x reference)
//
#include <hip/hip_runtime.h>
#include <cstddef>

#define T_LEN 1000
#define B_SZ 64
#define C_IN_ 12
#define D_MODEL_ 128
#define D_INNER_ 256
#define D_STATE_ 16
#define DT_RANK_ 8
#define N_CLS 5

typedef __attribute__((ext_vector_type(8))) short bf16x8;
typedef __attribute__((ext_vector_type(8))) unsigned short u16x8;
typedef __attribute__((ext_vector_type(4))) float f32x4;

__device__ __forceinline__ float fast_exp2(float x) {
#if __has_builtin(__builtin_amdgcn_exp2f)
  return __builtin_amdgcn_exp2f(x);
#else
  float r; asm volatile("v_exp_f32 %0, %1" : "=v"(r) : "v"(x)); return r;
#endif
}
__device__ __forceinline__ float fast_log2(float x) {
#if __has_builtin(__builtin_amdgcn_logf)
  return __builtin_amdgcn_logf(x);
#else
  float r; asm volatile("v_log_f32 %0, %1" : "=v"(r) : "v"(x)); return r;
#endif
}
__device__ __forceinline__ float fast_rcp(float x) {
#if __has_builtin(__builtin_amdgcn_rcpf)
  return __builtin_amdgcn_rcpf(x);
#else
  float r; asm volatile("v_rcp_f32 %0, %1" : "=v"(r) : "v"(x)); return r;
#endif
}
// silu via raw v_exp + v_rcp; arg bounded, under/overflow map to correct limits.
__device__ __forceinline__ float silu_f(float x) {
  float den = 1.f + fast_exp2(-x * 1.4426950408889634f);
  return x * fast_rcp(den);
}
// softplus via raw v_exp/v_log: |err| ~1e-7, far under downstream bf16-era tolerances.
__device__ __forceinline__ float softplus_f(float x) {
  const float L = 1.4426950408889634f, iL = 0.6931471805599453f;
  float e = fast_exp2(-fabsf(x) * L);
  float l = fast_log2(1.f + e) * iL;
  return fmaxf(x, 0.f) + l;
}
__device__ __forceinline__ unsigned short f2bf(float f) {
  unsigned u = __builtin_bit_cast(unsigned, f);
  u = u + 0x7FFFu + ((u >> 16) & 1u);   // RNE
  return (unsigned short)(u >> 16);
}
__device__ __forceinline__ float bf2f(unsigned short h) {
  unsigned u = ((unsigned)h) << 16;
  return __builtin_bit_cast(float, u);
}

// K0: h = x@ip_w.T + ip_b (bf16, MFMA-frag-packed, zero-filled t>=1000) + W pack.
__global__ __launch_bounds__(256) void k0_prep(
    const float* __restrict__ x, const float* __restrict__ ip_w,
    const float* __restrict__ ip_b, const float* __restrict__ in_proj_w,
    char* __restrict__ h_pk, char* __restrict__ w_pk)
{
  __shared__ unsigned short pk_s[8192];
  __shared__ unsigned short pkw_s[32768];
  const int tid = threadIdx.x;

  if (blockIdx.x == 16) {                    // W-pack block
    if (blockIdx.y != 0) return;
    const int n = tid;
    for (int k = 0; k < D_MODEL_; ++k) {
      unsigned short v = f2bf(in_proj_w[(size_t)n * D_MODEL_ + k]);
      int off = ((n >> 4) * 4 + (k >> 5)) * 512 + ((k & 31) >> 3) * 128
              + (n & 15) * 8 + (k & 7);
      pkw_s[off] = v;
    }
    __syncthreads();
    const float4* s4 = (const float4*)pkw_s;
    float4* dst = (float4*)w_pk;
#pragma unroll
    for (int q = 0; q < 16; ++q) dst[tid * 16 + q] = s4[tid * 16 + q];
    return;
  }

  const int tile4 = blockIdx.x;
  const int b = blockIdx.y;
  const int rl = tid & 63;
  const int kc = (tid >> 6) * 32;
  const int t = tile4 * 64 + rl;

  float xr[C_IN_] = {0.f, 0.f, 0.f, 0.f, 0.f, 0.f, 0.f, 0.f, 0.f, 0.f, 0.f, 0.f};
  const bool valid = (t < T_LEN);
  if (valid) {
    const float4* xp = (const float4*)(x + ((size_t)b * T_LEN + t) * C_IN_);
    float4 v0 = xp[0], v1 = xp[1], v2 = xp[2];
    xr[0] = v0.x; xr[1] = v0.y; xr[2] = v0.z;  xr[3] = v0.w;
    xr[4] = v1.x; xr[5] = v1.y; xr[6] = v1.z;  xr[7] = v1.w;
    xr[8] = v2.x; xr[9] = v2.y; xr[10] = v2.z; xr[11] = v2.w;
  }
  for (int kk = 0; kk < 32; ++kk) {
    const int k = kc + kk;
    unsigned short v = 0;
    if (valid) {
      float acc = ip_b[k];
      const float* wr = ip_w + k * C_IN_;
#pragma unroll
      for (int c = 0; c < C_IN_; ++c) acc += xr[c] * wr[c];
      v = f2bf(acc);
    }
    int off = (rl >> 4) * 2048 + (k >> 5) * 512 + ((k & 31) >> 3) * 128
            + (rl & 15) * 8 + (k & 7);
    pk_s[off] = v;
  }
  __syncthreads();
  const float4* s4 = (const float4*)pk_s;
  float4* dst = (float4*)(h_pk + (size_t)(b * 64 + tile4 * 4) * 4096);
#pragma unroll
  for (int q = 0; q < 4; ++q) dst[tid * 4 + q] = s4[tid * 4 + q];
}

// K1 v9: MFMA bf16 GEMM + halo + causal conv + fast-silu -> u (fp32).
__global__ __launch_bounds__(256) void k1_u(
    const char* __restrict__ h_pk, const char* __restrict__ w_pk,
    const float* __restrict__ conv_w, const float* __restrict__ conv_b,
    float* __restrict__ u_out)
{
  __shared__ float xm[67][260];

  const int tile = blockIdx.x;
  const int b    = blockIdx.y;
  const int t0   = tile * 64;
  const int tid  = threadIdx.x;
  const int w    = tid >> 6;
  const int l    = tid & 63;

  {
    const char* achunk = h_pk + (size_t)(b * 64 + tile * 4 + w) * 4096;
    bf16x8 a0 = *(const bf16x8*)(achunk + 0 * 1024 + l * 16);
    bf16x8 a1 = *(const bf16x8*)(achunk + 1 * 1024 + l * 16);
    bf16x8 a2 = *(const bf16x8*)(achunk + 2 * 1024 + l * 16);
    bf16x8 a3 = *(const bf16x8*)(achunk + 3 * 1024 + l * 16);

    const int row_l = w * 16 + (l >> 4) * 4;
#pragma unroll
    for (int nt = 0; nt < 16; ++nt) {
      const char* wb = w_pk + (size_t)nt * 4096 + l * 16;
      bf16x8 b0 = *(const bf16x8*)(wb + 0 * 1024);
      bf16x8 b1 = *(const bf16x8*)(wb + 1 * 1024);
      bf16x8 b2 = *(const bf16x8*)(wb + 2 * 1024);
      bf16x8 b3 = *(const bf16x8*)(wb + 3 * 1024);
      f32x4 acc = {0.f, 0.f, 0.f, 0.f};
      acc = __builtin_amdgcn_mfma_f32_16x16x32_bf16(a0, b0, acc, 0, 0, 0);
      acc = __builtin_amdgcn_mfma_f32_16x16x32_bf16(a1, b1, acc, 0, 0, 0);
      acc = __builtin_amdgcn_mfma_f32_16x16x32_bf16(a2, b2, acc, 0, 0, 0);
      acc = __builtin_amdgcn_mfma_f32_16x16x32_bf16(a3, b3, acc, 0, 0, 0);
      const int col = nt * 16 + (l & 15);
#pragma unroll
      for (int r = 0; r < 4; ++r)
        xm[3 + row_l + r][col] = acc[r];
    }
  }

  {
    const int n = tid;
    float hac[3] = {0.f, 0.f, 0.f};
    if (tile > 0) {
      const char* wrow = w_pk + (size_t)(n >> 4) * 4096 + (n & 15) * 16;
#pragma unroll
      for (int kt = 0; kt < 4; ++kt)
#pragma unroll
        for (int lg = 0; lg < 4; ++lg) {
          u16x8 wv = *(const u16x8*)(wrow + kt * 1024 + lg * 256);
#pragma unroll
          for (int r = 0; r < 3; ++r) {
            const int t = t0 - 3 + r;
            const char* hc = h_pk + (size_t)(b * 64 + (t >> 4)) * 4096;
            u16x8 hv = *(const u16x8*)(hc + kt * 1024 + lg * 256 + (t & 15) * 16);
#pragma unroll
            for (int j = 0; j < 8; ++j) hac[r] += bf2f(hv[j]) * bf2f(wv[j]);
          }
        }
    }
#pragma unroll
    for (int r = 0; r < 3; ++r) xm[r][n] = hac[r];
  }
  __syncthreads();

  {
    const int n = tid;
    const float4 cw = *(const float4*)&conv_w[n * 4];
    const float  cb = conv_b[n];
    float x0 = xm[0][n], x1 = xm[1][n], x2 = xm[2][n];
    for (int i = 0; i < 64; ++i) {
      const int t = t0 + i;
      float x3 = xm[3 + i][n];
      if (t < T_LEN) {
        float s = cb + x0 * cw.x + x1 * cw.y + x2 * cw.z + x3 * cw.w;
        u_out[(((size_t)b * T_LEN + t) << 8) + n] = silu_f(s);
      }
      x0 = x1; x1 = x2; x2 = x3;
    }
  }
}

// K3 v8: phase1 dbc = u @ xp[0:24].T; phase2 thread-per-d emits delta/du as
// F32 TIME-PACKED pk[b][t/4][d][4] (k4 reads float4 per 4 steps, no extracts);
// bm packed pk_bm[b][t/4][n][4].
__global__ __launch_bounds__(256) void k3_delta(
    const float* __restrict__ u, const float* __restrict__ x_proj_w,
    const float* __restrict__ dt_proj_w, const float* __restrict__ dt_proj_b,
    float* __restrict__ pk_delta, float* __restrict__ pk_du,
    float* __restrict__ pk_bm)
{
  __shared__ float4 xp4[24][65];
  __shared__ float dt_s[64][9];
  __shared__ float bm_s[64][17];

  const int row0 = blockIdx.x * 64;
  const int tid = threadIdx.x;

  for (int f = tid; f < 24 * 64; f += 256) {
    int c = f >> 6, k4 = f & 63;
    xp4[c][k4] = *(const float4*)&x_proj_w[(size_t)c * 256 + k4 * 4];
  }
  const float4 w0 = *(const float4*)&dt_proj_w[(size_t)tid * 8];
  const float4 w1 = *(const float4*)&dt_proj_w[(size_t)tid * 8 + 4];
  const float bias = dt_proj_b[tid];
  __syncthreads();

  // phase 1
  {
    const int r2 = tid >> 3, cg = tid & 7;
    const int ra = 2 * r2;
    const float4* ua4 = (const float4*)(u + (size_t)(row0 + ra) * 256);
    const float4* ub4 = (const float4*)(u + (size_t)(row0 + ra + 1) * 256);
    float a0 = 0.f, a1 = 0.f, a2 = 0.f, b0 = 0.f, b1 = 0.f, b2 = 0.f;
    for (int k4 = 0; k4 < 64; ++k4) {
      float4 a = ua4[k4], bb = ub4[k4];
      float4 q0 = xp4[cg * 3 + 0][k4];
      float4 q1 = xp4[cg * 3 + 1][k4];
      float4 q2 = xp4[cg * 3 + 2][k4];
      a0 += a.x * q0.x + a.y * q0.y + a.z * q0.z + a.w * q0.w;
      a1 += a.x * q1.x + a.y * q1.y + a.z * q1.z + a.w * q1.w;
      a2 += a.x * q2.x + a.y * q2.y + a.z * q2.z + a.w * q2.w;
      b0 += bb.x * q0.x + bb.y * q0.y + bb.z * q0.z + bb.w * q0.w;
      b1 += bb.x * q1.x + bb.y * q1.y + bb.z * q1.z + bb.w * q1.w;
      b2 += bb.x * q2.x + bb.y * q2.y + bb.z * q2.z + bb.w * q2.w;
    }
    float va[2][3] = {{a0, a1, a2}, {b0, b1, b2}};
#pragma unroll
    for (int rr = 0; rr < 2; ++rr)
#pragma unroll
      for (int c = 0; c < 3; ++c) {
        int col = cg * 3 + c;
        int row = ra + rr;
        if (col < 8) dt_s[row][col] = va[rr][c];
        else bm_s[row][col - 8] = va[rr][c];
      }
  }
  __syncthreads();

  // phase 2: thread = d; groups of 8 rows -> two float4 stores per array
  for (int g = 0; g < 8; ++g) {
    float dd[8], uu[8];
#pragma unroll
    for (int j = 0; j < 8; ++j) {
      int r = g * 8 + j;
      float pre = bias
        + dt_s[r][0] * w0.x + dt_s[r][1] * w0.y + dt_s[r][2] * w0.z + dt_s[r][3] * w0.w
        + dt_s[r][4] * w1.x + dt_s[r][5] * w1.y + dt_s[r][6] * w1.z + dt_s[r][7] * w1.w;
      float dlt = softplus_f(pre);
      size_t o = (size_t)(row0 + r) * 256 + tid;
      dd[j] = dlt;
      uu[j] = dlt * u[o];
    }
    int row = row0 + g * 8;
    int bb_ = row / 1000;
    int t   = row - bb_ * 1000;          // multiple of 8
    size_t base = (((size_t)bb_ * 250 + (t >> 2)) * 256 + tid) * 4;
    *(float4*)&pk_delta[base]        = make_float4(dd[0], dd[1], dd[2], dd[3]);
    *(float4*)&pk_delta[base + 1024] = make_float4(dd[4], dd[5], dd[6], dd[7]);
    *(float4*)&pk_du[base]           = make_float4(uu[0], uu[1], uu[2], uu[3]);
    *(float4*)&pk_du[base + 1024]    = make_float4(uu[4], uu[5], uu[6], uu[7]);
  }
  if (tid < 16) {
    for (int g = 0; g < 8; ++g) {
      float pb[8];
#pragma unroll
      for (int j = 0; j < 8; ++j) pb[j] = bm_s[g * 8 + j][tid];
      int row = row0 + g * 8;
      int bb_ = row / 1000;
      int t   = row - bb_ * 1000;
      size_t base = (((size_t)bb_ * 250 + (t >> 2)) * 16 + tid) * 4;
      *(float4*)&pk_bm[base]      = make_float4(pb[0], pb[1], pb[2], pb[3]);
      *(float4*)&pk_bm[base + 64] = make_float4(pb[4], pb[5], pb[6], pb[7]);
    }
  }
}

// K4 v10: f32 time-packed b128 reads (no extracts) + raw v_exp.
// Per step: mul(arg), exp, mul(t), fma -- the algorithmic floor.
__global__ __launch_bounds__(256) void k4_scan(
    const float* __restrict__ pk_delta, const float* __restrict__ pk_du,
    const float* __restrict__ pk_bm, const float* __restrict__ A_log,
    float* __restrict__ state_out)
{
  const int d0 = blockIdx.x * 16;
  const int b  = blockIdx.y;
  const int tid = threadIdx.x;
  const int dl = tid >> 4;
  const int n  = tid & 15;
  const int d  = d0 + dl;

  const float A2 = -expf(A_log[(size_t)d * 16 + n]) * 1.4426950408889634f;
  float s = 0.f;

  const float* dp = pk_delta + ((size_t)b * 250 * 256 + d) * 4;
  const float* xp = pk_du    + ((size_t)b * 250 * 256 + d) * 4;
  const float* bp = pk_bm    + ((size_t)b * 250 * 16 + n) * 4;

#pragma unroll 2
  for (int t4 = 0; t4 < 250; ++t4) {
    float4 dv = *(const float4*)(dp + (size_t)t4 * 1024);
    float4 xv = *(const float4*)(xp + (size_t)t4 * 1024);
    float4 bv = *(const float4*)(bp + (size_t)t4 * 64);
    s = fast_exp2(dv.x * A2) * s + xv.x * bv.x;
    s = fast_exp2(dv.y * A2) * s + xv.y * bv.y;
    s = fast_exp2(dv.z * A2) * s + xv.z * bv.z;
    s = fast_exp2(dv.w * A2) * s + xv.w * bv.w;
  }
  state_out[((size_t)b * 256 + d) * 16 + n] = s;
}

// K5: per-batch head.
__global__ __launch_bounds__(256) void k5_head(
    const float* __restrict__ x, const float* __restrict__ ip_w,
    const float* __restrict__ ip_b, const float* __restrict__ in_proj_w,
    const float* __restrict__ x_proj_w, const float* __restrict__ u,
    const float* __restrict__ state, const float* __restrict__ D_skip,
    const float* __restrict__ out_proj_w, const float* __restrict__ fc1_w,
    const float* __restrict__ fc1_b, const float* __restrict__ fc2_w,
    const float* __restrict__ fc2_b, float* __restrict__ out)
{
  const int b = blockIdx.x, tid = threadIdx.x;
  __shared__ float hl[128], ul[256], zs[256], cm[16], yv[256], ov[128], hid[64];
  if (tid < 128) {
    float acc = ip_b[tid];
    const float* xr = x + ((size_t)b * T_LEN + (T_LEN - 1)) * C_IN_;
#pragma unroll
    for (int c = 0; c < C_IN_; ++c) acc += xr[c] * ip_w[tid * C_IN_ + c];
    hl[tid] = acc;
  }
  ul[tid] = u[((size_t)b * T_LEN + (T_LEN - 1)) * 256 + tid];
  __syncthreads();
  {
    float acc = 0.f;
    const float4* wv = (const float4*)(in_proj_w + (size_t)(256 + tid) * 128);
    const float4* h4 = (const float4*)hl;
    for (int k = 0; k < 32; ++k) {
      float4 a = wv[k], c = h4[k];
      acc += c.x * a.x + c.y * a.y + c.z * a.z + c.w * a.w;
    }
    zs[tid] = silu_f(acc);
  }
  if (tid < 16) {
    float acc = 0.f;
    const float4* wv = (const float4*)(x_proj_w + (size_t)(24 + tid) * 256);
    const float4* u4 = (const float4*)ul;
    for (int k = 0; k < 64; ++k) {
      float4 a = wv[k], c = u4[k];
      acc += c.x * a.x + c.y * a.y + c.z * a.z + c.w * a.w;
    }
    cm[tid] = acc;
  }
  __syncthreads();
  {
    const float* st = state + ((size_t)b * 256 + tid) * 16;
    float acc = 0.f;
#pragma unroll
    for (int n = 0; n < 16; ++n) acc += st[n] * cm[n];
    yv[tid] = (acc + ul[tid] * D_skip[tid]) * zs[tid];
  }
  __syncthreads();
  if (tid < 128) {
    float acc = 0.f;
    const float4* wv = (const float4*)(out_proj_w + (size_t)tid * 256);
    const float4* y4 = (const float4*)yv;
    for (int k = 0; k < 64; ++k) {
      float4 a = wv[k], c = y4[k];
      acc += c.x * a.x + c.y * a.y + c.z * a.z + c.w * a.w;
    }
    ov[tid] = acc;
  }
  __syncthreads();
  if (tid < 64) {
    float acc = fc1_b[tid];
    const float4* wv = (const float4*)(fc1_w + (size_t)tid * 128);
    const float4* o4 = (const float4*)ov;
    for (int k = 0; k < 32; ++k) {
      float4 a = wv[k], c = o4[k];
      acc += c.x * a.x + c.y * a.y + c.z * a.z + c.w * a.w;
    }
    hid[tid] = fmaxf(acc, 0.f);
  }
  __syncthreads();
  if (tid < N_CLS) {
    float acc = fc2_b[tid];
    const float* wv = fc2_w + (size_t)tid * 64;
    for (int k = 0; k < 64; ++k) acc += hid[k] * wv[k];
    out[b * N_CLS + tid] = acc;
  }
}

extern "C" void kernel_launch(void* const* d_in, const int* in_sizes, int n_in,
                              void* d_out, int out_size, void* d_ws, size_t ws_size,
                              hipStream_t stream) {
  (void)in_sizes; (void)n_in; (void)out_size; (void)ws_size;
  const float* x         = (const float*)d_in[0];
  const float* ip_w      = (const float*)d_in[1];
  const float* ip_b      = (const float*)d_in[2];
  const float* in_proj_w = (const float*)d_in[3];
  const float* conv_w    = (const float*)d_in[4];
  const float* conv_b    = (const float*)d_in[5];
  const float* x_proj_w  = (const float*)d_in[6];
  const float* dt_proj_w = (const float*)d_in[7];
  const float* dt_proj_b = (const float*)d_in[8];
  const float* A_log     = (const float*)d_in[9];
  const float* D_skip    = (const float*)d_in[10];
  const float* out_proj_w= (const float*)d_in[11];
  const float* fc1_w     = (const float*)d_in[12];
  const float* fc1_b     = (const float*)d_in[13];
  const float* fc2_w     = (const float*)d_in[14];
  const float* fc2_b     = (const float*)d_in[15];
  float* out = (float*)d_out;

  float* u     = (float*)d_ws;                 // 16,384,000 f32 (65.5 MB)
  float* delta = u + (size_t)16384000;         // 16,384,000 f32 packed [b][250][d][4]
  float* du    = delta + (size_t)16384000;     // 16,384,000 f32 packed
  float* bm    = du + (size_t)16384000;        // 1,024,000 f32 packed [b][250][n][4]
  float* state = bm + (size_t)1024000;         // 262,144 f32   (total 201.75 MB, proven)
  // transient aliases inside delta region (dead before k3 writes delta):
  char* h_pk = (char*)delta;                   // 16.8 MB
  char* w_pk = h_pk + (size_t)64 * 64 * 4096;  // 64 KB

  k0_prep<<<dim3(17, 64), 256, 0, stream>>>(x, ip_w, ip_b, in_proj_w, h_pk, w_pk);
  k1_u<<<dim3(16, 64), 256, 0, stream>>>(h_pk, w_pk, conv_w, conv_b, u);
  k3_delta<<<1000, 256, 0, stream>>>(u, x_proj_w, dt_proj_w, dt_proj_b, delta, du, bm);
  k4_scan<<<dim3(16, 64), 256, 0, stream>>>(delta, du, bm, A_log, state);
  k5_head<<<64, 256, 0, stream>>>(x, ip_w, ip_b, in_proj_w, x_proj_w, u, state,
                                  D_skip, out_proj_w, fc1_w, fc1_b, fc2_w, fc2_b, out);
}

// Round 13
// 219.718 us; speedup vs baseline: 1.0351x; 1.0351x over previous
//
#include <hip/hip_runtime.h>
#include <cstddef>

#define T_LEN 1000
#define B_SZ 64
#define C_IN_ 12
#define D_MODEL_ 128
#define D_INNER_ 256
#define D_STATE_ 16
#define DT_RANK_ 8
#define N_CLS 5
#define NCH 5       // scan time-chunks (200 steps each)
#define CT4 50      // float4 groups per chunk

typedef __attribute__((ext_vector_type(8))) short bf16x8;
typedef __attribute__((ext_vector_type(8))) unsigned short u16x8;
typedef __attribute__((ext_vector_type(4))) float f32x4;

__device__ __forceinline__ float fast_exp2(float x) {
#if __has_builtin(__builtin_amdgcn_exp2f)
  return __builtin_amdgcn_exp2f(x);
#else
  float r; asm volatile("v_exp_f32 %0, %1" : "=v"(r) : "v"(x)); return r;
#endif
}
__device__ __forceinline__ float fast_log2(float x) {
#if __has_builtin(__builtin_amdgcn_logf)
  return __builtin_amdgcn_logf(x);
#else
  float r; asm volatile("v_log_f32 %0, %1" : "=v"(r) : "v"(x)); return r;
#endif
}
__device__ __forceinline__ float fast_rcp(float x) {
#if __has_builtin(__builtin_amdgcn_rcpf)
  return __builtin_amdgcn_rcpf(x);
#else
  float r; asm volatile("v_rcp_f32 %0, %1" : "=v"(r) : "v"(x)); return r;
#endif
}
__device__ __forceinline__ float silu_f(float x) {
  float den = 1.f + fast_exp2(-x * 1.4426950408889634f);
  return x * fast_rcp(den);
}
__device__ __forceinline__ float softplus_f(float x) {
  const float L = 1.4426950408889634f, iL = 0.6931471805599453f;
  float e = fast_exp2(-fabsf(x) * L);
  float l = fast_log2(1.f + e) * iL;
  return fmaxf(x, 0.f) + l;
}
__device__ __forceinline__ unsigned short f2bf(float f) {
  unsigned u = __builtin_bit_cast(unsigned, f);
  u = u + 0x7FFFu + ((u >> 16) & 1u);   // RNE
  return (unsigned short)(u >> 16);
}
__device__ __forceinline__ float bf2f(unsigned short h) {
  unsigned u = ((unsigned)h) << 16;
  return __builtin_bit_cast(float, u);
}

// K0: h = x@ip_w.T + ip_b (bf16, MFMA-frag-packed, zero-filled t>=1000) + W pack.
__global__ __launch_bounds__(256) void k0_prep(
    const float* __restrict__ x, const float* __restrict__ ip_w,
    const float* __restrict__ ip_b, const float* __restrict__ in_proj_w,
    char* __restrict__ h_pk, char* __restrict__ w_pk)
{
  __shared__ unsigned short pk_s[8192];
  __shared__ unsigned short pkw_s[32768];
  const int tid = threadIdx.x;

  if (blockIdx.x == 16) {                    // W-pack block
    if (blockIdx.y != 0) return;
    const int n = tid;
    for (int k = 0; k < D_MODEL_; ++k) {
      unsigned short v = f2bf(in_proj_w[(size_t)n * D_MODEL_ + k]);
      int off = ((n >> 4) * 4 + (k >> 5)) * 512 + ((k & 31) >> 3) * 128
              + (n & 15) * 8 + (k & 7);
      pkw_s[off] = v;
    }
    __syncthreads();
    const float4* s4 = (const float4*)pkw_s;
    float4* dst = (float4*)w_pk;
#pragma unroll
    for (int q = 0; q < 16; ++q) dst[tid * 16 + q] = s4[tid * 16 + q];
    return;
  }

  const int tile4 = blockIdx.x;
  const int b = blockIdx.y;
  const int rl = tid & 63;
  const int kc = (tid >> 6) * 32;
  const int t = tile4 * 64 + rl;

  float xr[C_IN_] = {0.f, 0.f, 0.f, 0.f, 0.f, 0.f, 0.f, 0.f, 0.f, 0.f, 0.f, 0.f};
  const bool valid = (t < T_LEN);
  if (valid) {
    const float4* xp = (const float4*)(x + ((size_t)b * T_LEN + t) * C_IN_);
    float4 v0 = xp[0], v1 = xp[1], v2 = xp[2];
    xr[0] = v0.x; xr[1] = v0.y; xr[2] = v0.z;  xr[3] = v0.w;
    xr[4] = v1.x; xr[5] = v1.y; xr[6] = v1.z;  xr[7] = v1.w;
    xr[8] = v2.x; xr[9] = v2.y; xr[10] = v2.z; xr[11] = v2.w;
  }
  for (int kk = 0; kk < 32; ++kk) {
    const int k = kc + kk;
    unsigned short v = 0;
    if (valid) {
      float acc = ip_b[k];
      const float* wr = ip_w + k * C_IN_;
#pragma unroll
      for (int c = 0; c < C_IN_; ++c) acc += xr[c] * wr[c];
      v = f2bf(acc);
    }
    int off = (rl >> 4) * 2048 + (k >> 5) * 512 + ((k & 31) >> 3) * 128
            + (rl & 15) * 8 + (k & 7);
    pk_s[off] = v;
  }
  __syncthreads();
  const float4* s4 = (const float4*)pk_s;
  float4* dst = (float4*)(h_pk + (size_t)(b * 64 + tile4 * 4) * 4096);
#pragma unroll
  for (int q = 0; q < 4; ++q) dst[tid * 4 + q] = s4[tid * 4 + q];
}

// K1 v9 (unchanged): MFMA bf16 GEMM + halo + causal conv + fast-silu -> u.
__global__ __launch_bounds__(256) void k1_u(
    const char* __restrict__ h_pk, const char* __restrict__ w_pk,
    const float* __restrict__ conv_w, const float* __restrict__ conv_b,
    float* __restrict__ u_out)
{
  __shared__ float xm[67][260];

  const int tile = blockIdx.x;
  const int b    = blockIdx.y;
  const int t0   = tile * 64;
  const int tid  = threadIdx.x;
  const int w    = tid >> 6;
  const int l    = tid & 63;

  {
    const char* achunk = h_pk + (size_t)(b * 64 + tile * 4 + w) * 4096;
    bf16x8 a0 = *(const bf16x8*)(achunk + 0 * 1024 + l * 16);
    bf16x8 a1 = *(const bf16x8*)(achunk + 1 * 1024 + l * 16);
    bf16x8 a2 = *(const bf16x8*)(achunk + 2 * 1024 + l * 16);
    bf16x8 a3 = *(const bf16x8*)(achunk + 3 * 1024 + l * 16);

    const int row_l = w * 16 + (l >> 4) * 4;
#pragma unroll
    for (int nt = 0; nt < 16; ++nt) {
      const char* wb = w_pk + (size_t)nt * 4096 + l * 16;
      bf16x8 b0 = *(const bf16x8*)(wb + 0 * 1024);
      bf16x8 b1 = *(const bf16x8*)(wb + 1 * 1024);
      bf16x8 b2 = *(const bf16x8*)(wb + 2 * 1024);
      bf16x8 b3 = *(const bf16x8*)(wb + 3 * 1024);
      f32x4 acc = {0.f, 0.f, 0.f, 0.f};
      acc = __builtin_amdgcn_mfma_f32_16x16x32_bf16(a0, b0, acc, 0, 0, 0);
      acc = __builtin_amdgcn_mfma_f32_16x16x32_bf16(a1, b1, acc, 0, 0, 0);
      acc = __builtin_amdgcn_mfma_f32_16x16x32_bf16(a2, b2, acc, 0, 0, 0);
      acc = __builtin_amdgcn_mfma_f32_16x16x32_bf16(a3, b3, acc, 0, 0, 0);
      const int col = nt * 16 + (l & 15);
#pragma unroll
      for (int r = 0; r < 4; ++r)
        xm[3 + row_l + r][col] = acc[r];
    }
  }

  {
    const int n = tid;
    float hac[3] = {0.f, 0.f, 0.f};
    if (tile > 0) {
      const char* wrow = w_pk + (size_t)(n >> 4) * 4096 + (n & 15) * 16;
#pragma unroll
      for (int kt = 0; kt < 4; ++kt)
#pragma unroll
        for (int lg = 0; lg < 4; ++lg) {
          u16x8 wv = *(const u16x8*)(wrow + kt * 1024 + lg * 256);
#pragma unroll
          for (int r = 0; r < 3; ++r) {
            const int t = t0 - 3 + r;
            const char* hc = h_pk + (size_t)(b * 64 + (t >> 4)) * 4096;
            u16x8 hv = *(const u16x8*)(hc + kt * 1024 + lg * 256 + (t & 15) * 16);
#pragma unroll
            for (int j = 0; j < 8; ++j) hac[r] += bf2f(hv[j]) * bf2f(wv[j]);
          }
        }
    }
#pragma unroll
    for (int r = 0; r < 3; ++r) xm[r][n] = hac[r];
  }
  __syncthreads();

  {
    const int n = tid;
    const float4 cw = *(const float4*)&conv_w[n * 4];
    const float  cb = conv_b[n];
    float x0 = xm[0][n], x1 = xm[1][n], x2 = xm[2][n];
    for (int i = 0; i < 64; ++i) {
      const int t = t0 + i;
      float x3 = xm[3 + i][n];
      if (t < T_LEN) {
        float s = cb + x0 * cw.x + x1 * cw.y + x2 * cw.z + x3 * cw.w;
        u_out[(((size_t)b * T_LEN + t) << 8) + n] = silu_f(s);
      }
      x0 = x1; x1 = x2; x2 = x3;
    }
  }
}

// K3 v9: phase1 dbc = u @ xp[0:24].T; phase2 thread-per-d emits delta/du as
// f32 time-packed pk[b][t/4][d][4]; bm packed pk_bm[b][t/4][n][4]; ALSO stashes
// u_last[b][d] so u is dead after this kernel (k4 aliases Q/P into it).
__global__ __launch_bounds__(256) void k3_delta(
    const float* __restrict__ u, const float* __restrict__ x_proj_w,
    const float* __restrict__ dt_proj_w, const float* __restrict__ dt_proj_b,
    float* __restrict__ pk_delta, float* __restrict__ pk_du,
    float* __restrict__ pk_bm, float* __restrict__ u_last)
{
  __shared__ float4 xp4[24][65];
  __shared__ float dt_s[64][9];
  __shared__ float bm_s[64][17];

  const int row0 = blockIdx.x * 64;
  const int tid = threadIdx.x;

  for (int f = tid; f < 24 * 64; f += 256) {
    int c = f >> 6, k4 = f & 63;
    xp4[c][k4] = *(const float4*)&x_proj_w[(size_t)c * 256 + k4 * 4];
  }
  const float4 w0 = *(const float4*)&dt_proj_w[(size_t)tid * 8];
  const float4 w1 = *(const float4*)&dt_proj_w[(size_t)tid * 8 + 4];
  const float bias = dt_proj_b[tid];
  __syncthreads();

  // phase 1
  {
    const int r2 = tid >> 3, cg = tid & 7;
    const int ra = 2 * r2;
    const float4* ua4 = (const float4*)(u + (size_t)(row0 + ra) * 256);
    const float4* ub4 = (const float4*)(u + (size_t)(row0 + ra + 1) * 256);
    float a0 = 0.f, a1 = 0.f, a2 = 0.f, b0 = 0.f, b1 = 0.f, b2 = 0.f;
    for (int k4 = 0; k4 < 64; ++k4) {
      float4 a = ua4[k4], bb = ub4[k4];
      float4 q0 = xp4[cg * 3 + 0][k4];
      float4 q1 = xp4[cg * 3 + 1][k4];
      float4 q2 = xp4[cg * 3 + 2][k4];
      a0 += a.x * q0.x + a.y * q0.y + a.z * q0.z + a.w * q0.w;
      a1 += a.x * q1.x + a.y * q1.y + a.z * q1.z + a.w * q1.w;
      a2 += a.x * q2.x + a.y * q2.y + a.z * q2.z + a.w * q2.w;
      b0 += bb.x * q0.x + bb.y * q0.y + bb.z * q0.z + bb.w * q0.w;
      b1 += bb.x * q1.x + bb.y * q1.y + bb.z * q1.z + bb.w * q1.w;
      b2 += bb.x * q2.x + bb.y * q2.y + bb.z * q2.z + bb.w * q2.w;
    }
    float va[2][3] = {{a0, a1, a2}, {b0, b1, b2}};
#pragma unroll
    for (int rr = 0; rr < 2; ++rr)
#pragma unroll
      for (int c = 0; c < 3; ++c) {
        int col = cg * 3 + c;
        int row = ra + rr;
        if (col < 8) dt_s[row][col] = va[rr][c];
        else bm_s[row][col - 8] = va[rr][c];
      }
  }
  __syncthreads();

  // phase 2: thread = d; groups of 8 rows -> two float4 stores per array
  for (int g = 0; g < 8; ++g) {
    float dd[8], uu[8];
#pragma unroll
    for (int j = 0; j < 8; ++j) {
      int r = g * 8 + j;
      float pre = bias
        + dt_s[r][0] * w0.x + dt_s[r][1] * w0.y + dt_s[r][2] * w0.z + dt_s[r][3] * w0.w
        + dt_s[r][4] * w1.x + dt_s[r][5] * w1.y + dt_s[r][6] * w1.z + dt_s[r][7] * w1.w;
      float dlt = softplus_f(pre);
      size_t o = (size_t)(row0 + r) * 256 + tid;
      float uv = u[o];
      dd[j] = dlt;
      uu[j] = dlt * uv;
      int rowg = row0 + r;
      if ((rowg - (rowg / 1000) * 1000) == 999)
        u_last[(rowg / 1000) * 256 + tid] = uv;
    }
    int row = row0 + g * 8;
    int bb_ = row / 1000;
    int t   = row - bb_ * 1000;          // multiple of 8
    size_t base = (((size_t)bb_ * 250 + (t >> 2)) * 256 + tid) * 4;
    *(float4*)&pk_delta[base]        = make_float4(dd[0], dd[1], dd[2], dd[3]);
    *(float4*)&pk_delta[base + 1024] = make_float4(dd[4], dd[5], dd[6], dd[7]);
    *(float4*)&pk_du[base]           = make_float4(uu[0], uu[1], uu[2], uu[3]);
    *(float4*)&pk_du[base + 1024]    = make_float4(uu[4], uu[5], uu[6], uu[7]);
  }
  if (tid < 16) {
    for (int g = 0; g < 8; ++g) {
      float pb[8];
#pragma unroll
      for (int j = 0; j < 8; ++j) pb[j] = bm_s[g * 8 + j][tid];
      int row = row0 + g * 8;
      int bb_ = row / 1000;
      int t   = row - bb_ * 1000;
      size_t base = (((size_t)bb_ * 250 + (t >> 2)) * 16 + tid) * 4;
      *(float4*)&pk_bm[base]      = make_float4(pb[0], pb[1], pb[2], pb[3]);
      *(float4*)&pk_bm[base + 64] = make_float4(pb[4], pb[5], pb[6], pb[7]);
    }
  }
}

// K4 v11: T-split into NCH chunks (affine transition s_out = P*s_in + Q;
// P = exp2(A2 * sum(delta))). 5120 blocks -> full occupancy, + 1-iter
// register prefetch. Writes Q,P per (chunk, channel).
__global__ __launch_bounds__(256) void k4_scan(
    const float* __restrict__ pk_delta, const float* __restrict__ pk_du,
    const float* __restrict__ pk_bm, const float* __restrict__ A_log,
    float* __restrict__ Qb, float* __restrict__ Pb)
{
  const int d0 = blockIdx.x * 16;
  const int b  = blockIdx.y;
  const int c  = blockIdx.z;
  const int tid = threadIdx.x;
  const int dl = tid >> 4;
  const int n  = tid & 15;
  const int d  = d0 + dl;

  const float A2 = -expf(A_log[(size_t)d * 16 + n]) * 1.4426950408889634f;
  float s = 0.f, sum = 0.f;

  const float* dp = pk_delta + ((size_t)b * 250 * 256 + d) * 4 + (size_t)c * CT4 * 1024;
  const float* xp = pk_du    + ((size_t)b * 250 * 256 + d) * 4 + (size_t)c * CT4 * 1024;
  const float* bp = pk_bm    + ((size_t)b * 250 * 16 + n) * 4 + (size_t)c * CT4 * 64;

  float4 dv = *(const float4*)dp;
  float4 xv = *(const float4*)xp;
  float4 bv = *(const float4*)bp;
  for (int i = 0; i < CT4 - 1; ++i) {
    float4 dvn = *(const float4*)(dp + (size_t)(i + 1) * 1024);
    float4 xvn = *(const float4*)(xp + (size_t)(i + 1) * 1024);
    float4 bvn = *(const float4*)(bp + (size_t)(i + 1) * 64);
    sum += (dv.x + dv.y) + (dv.z + dv.w);
    s = fast_exp2(dv.x * A2) * s + xv.x * bv.x;
    s = fast_exp2(dv.y * A2) * s + xv.y * bv.y;
    s = fast_exp2(dv.z * A2) * s + xv.z * bv.z;
    s = fast_exp2(dv.w * A2) * s + xv.w * bv.w;
    dv = dvn; xv = xvn; bv = bvn;
  }
  sum += (dv.x + dv.y) + (dv.z + dv.w);
  s = fast_exp2(dv.x * A2) * s + xv.x * bv.x;
  s = fast_exp2(dv.y * A2) * s + xv.y * bv.y;
  s = fast_exp2(dv.z * A2) * s + xv.z * bv.z;
  s = fast_exp2(dv.w * A2) * s + xv.w * bv.w;

  const size_t o = (size_t)c * 262144 + (size_t)b * 4096 + (size_t)d0 * 16 + tid;
  Qb[o] = s;
  Pb[o] = fast_exp2(A2 * sum);
}

// K4b: fold the NCH affine transitions -> final state.
__global__ __launch_bounds__(256) void k4b_combine(
    const float* __restrict__ Qb, const float* __restrict__ Pb,
    float* __restrict__ state_out)
{
  const size_t g = (size_t)blockIdx.x * 256 + threadIdx.x;   // 1024 blocks
  float s = Qb[g];
#pragma unroll
  for (int c = 1; c < NCH; ++c)
    s = Qb[(size_t)c * 262144 + g] + Pb[(size_t)c * 262144 + g] * s;
  state_out[g] = s;
}

// K5: per-batch head (ul now from u_last; u itself is dead/aliased by k4).
__global__ __launch_bounds__(256) void k5_head(
    const float* __restrict__ x, const float* __restrict__ ip_w,
    const float* __restrict__ ip_b, const float* __restrict__ in_proj_w,
    const float* __restrict__ x_proj_w, const float* __restrict__ u_last,
    const float* __restrict__ state, const float* __restrict__ D_skip,
    const float* __restrict__ out_proj_w, const float* __restrict__ fc1_w,
    const float* __restrict__ fc1_b, const float* __restrict__ fc2_w,
    const float* __restrict__ fc2_b, float* __restrict__ out)
{
  const int b = blockIdx.x, tid = threadIdx.x;
  __shared__ float hl[128], ul[256], zs[256], cm[16], yv[256], ov[128], hid[64];
  if (tid < 128) {
    float acc = ip_b[tid];
    const float* xr = x + ((size_t)b * T_LEN + (T_LEN - 1)) * C_IN_;
#pragma unroll
    for (int c = 0; c < C_IN_; ++c) acc += xr[c] * ip_w[tid * C_IN_ + c];
    hl[tid] = acc;
  }
  ul[tid] = u_last[b * 256 + tid];
  __syncthreads();
  {
    float acc = 0.f;
    const float4* wv = (const float4*)(in_proj_w + (size_t)(256 + tid) * 128);
    const float4* h4 = (const float4*)hl;
    for (int k = 0; k < 32; ++k) {
      float4 a = wv[k], c = h4[k];
      acc += c.x * a.x + c.y * a.y + c.z * a.z + c.w * a.w;
    }
    zs[tid] = silu_f(acc);
  }
  if (tid < 16) {
    float acc = 0.f;
    const float4* wv = (const float4*)(x_proj_w + (size_t)(24 + tid) * 256);
    const float4* u4 = (const float4*)ul;
    for (int k = 0; k < 64; ++k) {
      float4 a = wv[k], c = u4[k];
      acc += c.x * a.x + c.y * a.y + c.z * a.z + c.w * a.w;
    }
    cm[tid] = acc;
  }
  __syncthreads();
  {
    const float* st = state + ((size_t)b * 256 + tid) * 16;
    float acc = 0.f;
#pragma unroll
    for (int n = 0; n < 16; ++n) acc += st[n] * cm[n];
    yv[tid] = (acc + ul[tid] * D_skip[tid]) * zs[tid];
  }
  __syncthreads();
  if (tid < 128) {
    float acc = 0.f;
    const float4* wv = (const float4*)(out_proj_w + (size_t)tid * 256);
    const float4* y4 = (const float4*)yv;
    for (int k = 0; k < 64; ++k) {
      float4 a = wv[k], c = y4[k];
      acc += c.x * a.x + c.y * a.y + c.z * a.z + c.w * a.w;
    }
    ov[tid] = acc;
  }
  __syncthreads();
  if (tid < 64) {
    float acc = fc1_b[tid];
    const float4* wv = (const float4*)(fc1_w + (size_t)tid * 128);
    const float4* o4 = (const float4*)ov;
    for (int k = 0; k < 32; ++k) {
      float4 a = wv[k], c = o4[k];
      acc += c.x * a.x + c.y * a.y + c.z * a.z + c.w * a.w;
    }
    hid[tid] = fmaxf(acc, 0.f);
  }
  __syncthreads();
  if (tid < N_CLS) {
    float acc = fc2_b[tid];
    const float* wv = fc2_w + (size_t)tid * 64;
    for (int k = 0; k < 64; ++k) acc += hid[k] * wv[k];
    out[b * N_CLS + tid] = acc;
  }
}

extern "C" void kernel_launch(void* const* d_in, const int* in_sizes, int n_in,
                              void* d_out, int out_size, void* d_ws, size_t ws_size,
                              hipStream_t stream) {
  (void)in_sizes; (void)n_in; (void)out_size; (void)ws_size;
  const float* x         = (const float*)d_in[0];
  const float* ip_w      = (const float*)d_in[1];
  const float* ip_b      = (const float*)d_in[2];
  const float* in_proj_w = (const float*)d_in[3];
  const float* conv_w    = (const float*)d_in[4];
  const float* conv_b    = (const float*)d_in[5];
  const float* x_proj_w  = (const float*)d_in[6];
  const float* dt_proj_w = (const float*)d_in[7];
  const float* dt_proj_b = (const float*)d_in[8];
  const float* A_log     = (const float*)d_in[9];
  const float* D_skip    = (const float*)d_in[10];
  const float* out_proj_w= (const float*)d_in[11];
  const float* fc1_w     = (const float*)d_in[12];
  const float* fc1_b     = (const float*)d_in[13];
  const float* fc2_w     = (const float*)d_in[14];
  const float* fc2_b     = (const float*)d_in[15];
  float* out = (float*)d_out;

  float* u      = (float*)d_ws;                 // 16,384,000 f32 (65.5 MB)
  float* delta  = u + (size_t)16384000;         // 16,384,000 f32 packed [b][250][d][4]
  float* du     = delta + (size_t)16384000;     // 16,384,000 f32 packed
  float* bm     = du + (size_t)16384000;        // 1,024,000 f32 packed [b][250][n][4]
  float* state  = bm + (size_t)1024000;         // 262,144 f32
  float* u_last = state + (size_t)262144;       // 16,384 f32 (total ~201.8 MB)
  // aliases into regions dead at their use time:
  char* h_pk = (char*)delta;                    // k0..k1 (delta written later by k3)
  char* w_pk = h_pk + (size_t)64 * 64 * 4096;
  float* Qb  = u;                               // k4..k4b (u dead after k3)
  float* Pb  = u + (size_t)2000000;             // 5*262144 = 1.31M floats each

  k0_prep<<<dim3(17, 64), 256, 0, stream>>>(x, ip_w, ip_b, in_proj_w, h_pk, w_pk);
  k1_u<<<dim3(16, 64), 256, 0, stream>>>(h_pk, w_pk, conv_w, conv_b, u);
  k3_delta<<<1000, 256, 0, stream>>>(u, x_proj_w, dt_proj_w, dt_proj_b,
                                     delta, du, bm, u_last);
  k4_scan<<<dim3(16, 64, NCH), 256, 0, stream>>>(delta, du, bm, A_log, Qb, Pb);
  k4b_combine<<<1024, 256, 0, stream>>>(Qb, Pb, state);
  k5_head<<<64, 256, 0, stream>>>(x, ip_w, ip_b, in_proj_w, x_proj_w, u_last, state,
                                  D_skip, out_proj_w, fc1_w, fc1_b, fc2_w, fc2_b, out);
}